// Round 7
// baseline (2086.387 us; speedup 1.0000x reference)
//
#include <hip/hip_runtime.h>
#include <hip/hip_bf16.h>
#include <stdint.h>

#define VOCAB 32000
#define HID 512
#define NB 8
#define SEQ 512
#define NG 1536
#define LN_EPS 1e-5f
#define GRU_WGS 32
#define GRU_SPIN_BUDGET (1 << 20)

typedef short bf16x8 __attribute__((ext_vector_type(8)));
typedef float f32x4 __attribute__((ext_vector_type(4)));

__device__ __forceinline__ unsigned short f2bf(float f) {
  union { float f; uint32_t u; } c; c.f = f;
  return (unsigned short)((c.u + 0x7fffu + ((c.u >> 16) & 1u)) >> 16);
}

// ---------------- init workspace ---------------------------------------------
// h_state = 2 buffers of [16][HID] bf16, generation tag in bit0 of EVERY dword
// (LSB of each even-col bf16). buf0 = 0.0 with tag 0 = valid h_0 for step-0
// readers (texp(0)=0). buf1 = 0x00010001 (tag 1) = invalid for step-1 readers
// (texp(1)=0) until step-0 publishers overwrite with h_1 (tpub=0).
__global__ void init_ws_kernel(uint32_t* h_state) {
  int i = blockIdx.x * 256 + threadIdx.x;
  if (i < 8 * HID) h_state[i] = 0u;                 // buf0 (8*HID dwords)
  else if (i < 16 * HID) h_state[i] = 0x00010001u;  // buf1
}

// ---------------- fp32 -> bf16 bulk convert ---------------------------------
__global__ void conv_bf16_kernel(const float* __restrict__ in,
                                 unsigned short* __restrict__ out, int n4) {
  int i = blockIdx.x * 256 + threadIdx.x;
  if (i >= n4) return;
  const float4 v = ((const float4*)in)[i];
  ushort4 o;
  o.x = f2bf(v.x); o.y = f2bf(v.y); o.z = f2bf(v.z); o.w = f2bf(v.w);
  ((ushort4*)out)[i] = o;
}

// ---------------- embedding gather -> bf16 A matrix [4096][512] -------------
__global__ void embed_kernel(const int* __restrict__ ids,
                             const float* __restrict__ emb,
                             unsigned short* __restrict__ out) {
  int row = blockIdx.x;
  int id = ids[row];
  int c = threadIdx.x * 2;
  const float2 v = *(const float2*)(emb + (size_t)id * HID + c);
  ushort2 o; o.x = f2bf(v.x); o.y = f2bf(v.y);
  *(ushort2*)(out + (size_t)row * HID + c) = o;
}

// ---------------- bf16 GEMM: C[M][N] = A[M][K] * B[N][K]^T + bias -----------
#define BM 128
#define BN 128
#define BK 32

__global__ __launch_bounds__(256, 2) void gemm_bt_kernel(
    const unsigned short* __restrict__ A, const unsigned short* __restrict__ B,
    const float* __restrict__ bias, float* __restrict__ C, int N, int nbn) {
  __shared__ unsigned short a_lds[BM * BK];
  __shared__ unsigned short b_lds[BN * BK];
  const int nwg = gridDim.x;
  const int chunk = nwg >> 3;
  const int bid = blockIdx.x;
  const int sw = (bid & 7) * chunk + (bid >> 3);
  const int bm = sw / nbn, bn = sw % nbn;
  const int tid = threadIdx.x;
  const int lane = tid & 63, wid = tid >> 6;
  const int wm = wid >> 1, wn = wid & 1;

  f32x4 acc[4][4] = {};

  for (int kt = 0; kt < HID / BK; ++kt) {
    __syncthreads();
#pragma unroll
    for (int p = 0; p < 2; ++p) {
      const int flat = (p * 256 + tid) * 16;  // byte offset in 8KB tile
      const int row = flat >> 6;              // 64B per row (32 bf16)
      const int kb = flat & 63;
      const char* ga =
          (const char*)(A + ((size_t)(bm * BM + row) * HID + kt * BK)) + kb;
      const char* gb =
          (const char*)(B + ((size_t)(bn * BN + row) * HID + kt * BK)) + kb;
      char* la = (char*)a_lds + (size_t)(p * 256 + wid * 64) * 16;
      char* lb = (char*)b_lds + (size_t)(p * 256 + wid * 64) * 16;
      __builtin_amdgcn_global_load_lds(
          (const __attribute__((address_space(1))) void*)ga,
          (__attribute__((address_space(3))) void*)la, 16, 0, 0);
      __builtin_amdgcn_global_load_lds(
          (const __attribute__((address_space(1))) void*)gb,
          (__attribute__((address_space(3))) void*)lb, 16, 0, 0);
    }
    __syncthreads();
    bf16x8 af[4], bfr[4];
#pragma unroll
    for (int i = 0; i < 4; ++i) {
      af[i] = *(const bf16x8*)(a_lds + (wm * 64 + i * 16 + (lane & 15)) * BK +
                               (lane >> 4) * 8);
      bfr[i] = *(const bf16x8*)(b_lds + (wn * 64 + i * 16 + (lane & 15)) * BK +
                                (lane >> 4) * 8);
    }
#pragma unroll
    for (int i = 0; i < 4; ++i)
#pragma unroll
      for (int j = 0; j < 4; ++j)
        acc[i][j] =
            __builtin_amdgcn_mfma_f32_16x16x32_bf16(af[i], bfr[j], acc[i][j], 0, 0, 0);
  }
#pragma unroll
  for (int i = 0; i < 4; ++i) {
    const int mrow = bm * BM + wm * 64 + i * 16 + (lane >> 4) * 4;
#pragma unroll
    for (int j = 0; j < 4; ++j) {
      const int col = bn * BN + wn * 64 + j * 16 + (lane & 15);
      const float bv = bias[col];
#pragma unroll
      for (int r = 0; r < 4; ++r)
        C[(size_t)(mrow + r) * N + col] = acc[i][j][r] + bv;
    }
  }
}

// ---------------- persistent GRU scan: 1 wave/WG, tagged-data sync -----------
// 32 WGs x 64 threads. WG w owns h cols [w*16, w*16+16); all 3 gates' w_hh
// rows in 48 register B-frags; gate math in-register; zero barriers/fences/
// flags. Sync = the data (tag bit0 of every dword, parity T(s)=(s>>1)&1).
// Round-7 changes: (a) amdgpu_waves_per_eu(1) to unlock 512 VGPRs (kill the
// 256-cap spills), (b) poll-lite discovery (1 sentinel u64 per producer)
// before the validated bulk load, so the masked-reload loop runs ~once,
// (c) depth-2 xg register pipeline (loads for t+2 issued at bottom of iter t).
__global__ __attribute__((amdgpu_flat_work_group_size(64, 64),
                          amdgpu_waves_per_eu(1, 1)))
void gru_kernel(const float* __restrict__ xg, const float* __restrict__ w_hh,
                const float* __restrict__ b_hh, float* __restrict__ hs,
                unsigned short* h_state) {
  const int wid = blockIdx.x;
  const int lane = threadIdx.x;
  const int col16 = lane & 15;
  const int kq = lane >> 4;  // 0..3 : which 8-wide K slice of the 32-window

  __shared__ float h_pub[8][16];

  // pack all 3 gates' weights into 48 MFMA B-fragments (registers), once
  bf16x8 wf[3][16];
#pragma unroll
  for (int g = 0; g < 3; ++g) {
    const float* wr =
        w_hh + (size_t)(g * HID + wid * 16 + col16) * HID + kq * 8;
#pragma unroll
    for (int kk = 0; kk < 16; ++kk) {
      float4 f0 = *(const float4*)(wr + kk * 32);
      float4 f1 = *(const float4*)(wr + kk * 32 + 4);
      bf16x8 v;
      v[0] = (short)f2bf(f0.x); v[1] = (short)f2bf(f0.y);
      v[2] = (short)f2bf(f0.z); v[3] = (short)f2bf(f0.w);
      v[4] = (short)f2bf(f1.x); v[5] = (short)f2bf(f1.y);
      v[6] = (short)f2bf(f1.z); v[7] = (short)f2bf(f1.w);
      wf[g][kk] = v;
    }
  }
  const float bh_r = b_hh[0 * HID + wid * 16 + col16];
  const float bh_z = b_hh[1 * HID + wid * 16 + col16];
  const float bh_n = b_hh[2 * HID + wid * 16 + col16];

  const int abase = col16 * HID + kq * 8;  // A-frag: row=batch=col16, k=kq*8
  const bool realrow = col16 < 8;          // batches 8..15 are padding zeros
  const bool owner = lane < 32;            // lanes 0..31 own real (batch,col)
  const int bbase = kq * 4;                // first batch of this lane's C rows

  // depth-2 xg register pipeline: xc = step t, xn_ = step t+1
  float xc[12], xn_[12];
#pragma unroll
  for (int r = 0; r < 12; ++r) { xc[r] = 0.f; xn_[r] = 0.f; }
  if (owner) {
#pragma unroll
    for (int r = 0; r < 4; ++r) {
      const size_t xo = (size_t)(bbase + r) * SEQ * NG + wid * 16 + col16;
      xc[r] = xg[xo];
      xc[4 + r] = xg[xo + HID];
      xc[8 + r] = xg[xo + 2 * HID];
      xn_[r] = xg[xo + NG];
      xn_[4 + r] = xg[xo + NG + HID];
      xn_[8 + r] = xg[xo + NG + 2 * HID];
    }
  }
  float hprev[4] = {0.f, 0.f, 0.f, 0.f};
  int budget = GRU_SPIN_BUDGET;

  for (int t = 0; t < SEQ; ++t) {
    const unsigned short* rd = h_state + (size_t)(t & 1) * (16 * HID);
    unsigned short* wpub = h_state + (size_t)((t + 1) & 1) * (16 * HID);
    const uint32_t texp = (uint32_t)((t >> 1) & 1);
    const uint32_t tpub = (uint32_t)(((t + 1) >> 1) & 1);

    // ---- poll-lite discovery: 1 sentinel u64 per producer (lane=producer) --
    {
      bool okl = true;
      do {
        if (lane < 32) {
          const uint64_t* sp =
              (const uint64_t*)(rd + (lane & 7) * HID + lane * 16);
          const uint64_t s =
              __hip_atomic_load(sp, __ATOMIC_RELAXED, __HIP_MEMORY_SCOPE_AGENT);
          okl = ((((uint32_t)s ^ texp) | ((uint32_t)(s >> 32) ^ texp)) & 1u) ==
                0u;
        }
      } while (__ballot(okl) != ~0ULL && --budget > 0);
    }

    // ---- validated bulk load: 16 x uint4 (each = one MFMA A-frag) ----------
    uint4 hb[16];
#pragma unroll
    for (int kk = 0; kk < 16; ++kk) hb[kk] = make_uint4(0, 0, 0, 0);
    {
      uint32_t stale = realrow ? 0xFFFFu : 0u;
      do {
        if (stale) {
#pragma unroll
          for (int kk = 0; kk < 16; ++kk) {
            if (stale & (1u << kk)) {
              const uint4* ap = (const uint4*)(rd + abase + kk * 32);
              // uint4 load: per-dword tags validate each dword independently
              hb[kk].x = __hip_atomic_load((const uint32_t*)ap + 0,
                                           __ATOMIC_RELAXED,
                                           __HIP_MEMORY_SCOPE_AGENT);
              hb[kk].y = __hip_atomic_load((const uint32_t*)ap + 1,
                                           __ATOMIC_RELAXED,
                                           __HIP_MEMORY_SCOPE_AGENT);
              hb[kk].z = __hip_atomic_load((const uint32_t*)ap + 2,
                                           __ATOMIC_RELAXED,
                                           __HIP_MEMORY_SCOPE_AGENT);
              hb[kk].w = __hip_atomic_load((const uint32_t*)ap + 3,
                                           __ATOMIC_RELAXED,
                                           __HIP_MEMORY_SCOPE_AGENT);
            }
          }
#pragma unroll
          for (int kk = 0; kk < 16; ++kk) {
            const uint32_t bad = ((hb[kk].x ^ texp) | (hb[kk].y ^ texp) |
                                  (hb[kk].z ^ texp) | (hb[kk].w ^ texp)) &
                                 1u;
            if (!bad) stale &= ~(1u << kk);
          }
        }
      } while (__ballot(stale != 0u) != 0ULL && --budget > 0);
    }

    // ---- three gates, each split into 2 half-chains (6 accumulators) ----
    f32x4 ar0 = {0.f, 0.f, 0.f, 0.f}, ar1 = {0.f, 0.f, 0.f, 0.f};
    f32x4 az0 = {0.f, 0.f, 0.f, 0.f}, az1 = {0.f, 0.f, 0.f, 0.f};
    f32x4 an0 = {0.f, 0.f, 0.f, 0.f}, an1 = {0.f, 0.f, 0.f, 0.f};
#pragma unroll
    for (int kk = 0; kk < 16; kk += 2) {
      union { uint4 u; bf16x8 v; } c0, c1;
      c0.u = hb[kk];
      c1.u = hb[kk + 1];
      ar0 = __builtin_amdgcn_mfma_f32_16x16x32_bf16(c0.v, wf[0][kk], ar0, 0, 0, 0);
      az0 = __builtin_amdgcn_mfma_f32_16x16x32_bf16(c0.v, wf[1][kk], az0, 0, 0, 0);
      an0 = __builtin_amdgcn_mfma_f32_16x16x32_bf16(c0.v, wf[2][kk], an0, 0, 0, 0);
      ar1 = __builtin_amdgcn_mfma_f32_16x16x32_bf16(c1.v, wf[0][kk + 1], ar1, 0, 0, 0);
      az1 = __builtin_amdgcn_mfma_f32_16x16x32_bf16(c1.v, wf[1][kk + 1], az1, 0, 0, 0);
      an1 = __builtin_amdgcn_mfma_f32_16x16x32_bf16(c1.v, wf[2][kk + 1], an1, 0, 0, 0);
    }
    const f32x4 ar = ar0 + ar1, az = az0 + az1, an = an0 + an1;

    // ---- in-register gate math: lane owns (batch bbase+r, col col16) ----
    float hnew[4] = {0.f, 0.f, 0.f, 0.f};
    if (owner) {
#pragma unroll
      for (int r = 0; r < 4; ++r) {
        const float rg = 1.f / (1.f + __expf(-(xc[r] + ar[r] + bh_r)));
        const float zg = 1.f / (1.f + __expf(-(xc[4 + r] + az[r] + bh_z)));
        const float a = xc[8 + r] + rg * (an[r] + bh_n);
        const float e2 = __expf(-2.f * fabsf(a));
        const float nn = copysignf((1.f - e2) / (1.f + e2), a);
        hnew[r] = (1.f - zg) * nn + zg * hprev[r];
        hprev[r] = hnew[r];
        h_pub[bbase + r][col16] = hnew[r];
      }
    }
    asm volatile("s_waitcnt lgkmcnt(0)" ::: "memory");
    __builtin_amdgcn_sched_barrier(0);
    // ---- tagged publish: lane (b=lane>>2, q=lane&3) -> 4 cols as one u64 ----
    if (lane < 32) {
      const int tb = lane >> 2;
      const int tq = (lane & 3) * 4;
      const float4 hp = *(const float4*)&h_pub[tb][tq];
      union { unsigned short s[4]; uint64_t u; } pk;
      pk.s[0] = (unsigned short)((f2bf(hp.x) & ~(unsigned short)1) | tpub);
      pk.s[1] = f2bf(hp.y);
      pk.s[2] = (unsigned short)((f2bf(hp.z) & ~(unsigned short)1) | tpub);
      pk.s[3] = f2bf(hp.w);
      uint64_t* dst = (uint64_t*)(wpub + tb * HID + wid * 16 + tq);
      __hip_atomic_store(dst, pk.u, __ATOMIC_RELAXED,
                         __HIP_MEMORY_SCOPE_AGENT);
    }
    // ---- off-critical-path: hs output; rotate xg pipeline; load t+2 ----
    if (owner) {
#pragma unroll
      for (int r = 0; r < 4; ++r)
        hs[((size_t)(bbase + r) * SEQ + t) * HID + wid * 16 + col16] = hnew[r];
    }
#pragma unroll
    for (int r = 0; r < 12; ++r) xc[r] = xn_[r];
    if (owner && t + 2 < SEQ) {
#pragma unroll
      for (int r = 0; r < 4; ++r) {
        const size_t xo = (size_t)(bbase + r) * SEQ * NG +
                          (size_t)(t + 2) * NG + wid * 16 + col16;
        xn_[r] = xg[xo];
        xn_[4 + r] = xg[xo + HID];
        xn_[8 + r] = xg[xo + 2 * HID];
      }
    }
  }
}

// ---------------- LayerNorm rows of 512 -> bf16 ------------------------------
__global__ __launch_bounds__(256) void ln_kernel(
    const float* __restrict__ hs, const float* __restrict__ gamma,
    const float* __restrict__ beta, unsigned short* __restrict__ y) {
  const int row = blockIdx.x * 4 + (threadIdx.x >> 6);
  const int lane = threadIdx.x & 63;
  const float* x = hs + (size_t)row * HID + lane * 8;
  float v[8];
  *(float4*)v = *(const float4*)x;
  *(float4*)(v + 4) = *(const float4*)(x + 4);
  float s = 0.f, q = 0.f;
#pragma unroll
  for (int j = 0; j < 8; ++j) { s += v[j]; q += v[j] * v[j]; }
#pragma unroll
  for (int off = 32; off > 0; off >>= 1) {
    s += __shfl_xor(s, off);
    q += __shfl_xor(q, off);
  }
  const float mu = s * (1.f / 512.f);
  const float is = rsqrtf(q * (1.f / 512.f) - mu * mu + LN_EPS);
  const float* gp = gamma + lane * 8;
  const float* bp = beta + lane * 8;
  union { unsigned short o[8]; uint4 u; } pk;
#pragma unroll
  for (int j = 0; j < 8; ++j) pk.o[j] = f2bf((v[j] - mu) * is * gp[j] + bp[j]);
  *(uint4*)(y + (size_t)row * HID + lane * 8) = pk.u;
}

// ---------------- launch -----------------------------------------------------
extern "C" void kernel_launch(void* const* d_in, const int* in_sizes, int n_in,
                              void* d_out, int out_size, void* d_ws,
                              size_t ws_size, hipStream_t stream) {
  const int* ids = (const int*)d_in[0];
  const float* emb = (const float*)d_in[1];
  const float* w_ih = (const float*)d_in[2];
  const float* w_hh = (const float*)d_in[3];
  const float* b_ih = (const float*)d_in[4];
  const float* b_hh = (const float*)d_in[5];
  const float* gamma = (const float*)d_in[6];
  const float* beta = (const float*)d_in[7];
  const float* head_w = (const float*)d_in[8];
  const float* head_b = (const float*)d_in[9];
  float* out = (float*)d_out;

  char* ws = (char*)d_ws;
  size_t off = 0;
  auto alloc = [&](size_t bytes) -> void* {
    void* p = ws + off;
    off = (off + bytes + 255) & ~(size_t)255;
    return p;
  };
  unsigned short* h_state = (unsigned short*)alloc(2 * 16 * HID * 2);
  unsigned short* A1 = (unsigned short*)alloc((size_t)NB * SEQ * HID * 2);
  unsigned short* wihb = (unsigned short*)alloc((size_t)NG * HID * 2);
  unsigned short* hwb = (unsigned short*)alloc((size_t)VOCAB * HID * 2);
  float* xg = (float*)alloc((size_t)NB * SEQ * NG * 4);
  float* hsb = (float*)alloc((size_t)NB * SEQ * HID * 4);
  unsigned short* yb = (unsigned short*)alloc((size_t)NB * SEQ * HID * 2);

  init_ws_kernel<<<32, 256, 0, stream>>>((uint32_t*)h_state);
  conv_bf16_kernel<<<(NG * HID / 4) / 256, 256, 0, stream>>>(w_ih, wihb,
                                                             NG * HID / 4);
  conv_bf16_kernel<<<(VOCAB * HID / 4) / 256, 256, 0, stream>>>(
      head_w, hwb, VOCAB * HID / 4);
  embed_kernel<<<NB * SEQ, 256, 0, stream>>>(ids, emb, A1);
  // xg = A1 * w_ih^T + b_ih : M=4096, N=1536  (grid 32*12=384, %8==0)
  gemm_bt_kernel<<<(NB * SEQ / BM) * (NG / BN), 256, 0, stream>>>(
      A1, wihb, b_ih, xg, NG, NG / BN);
  gru_kernel<<<GRU_WGS, 64, 0, stream>>>(xg, w_hh, b_hh, hsb, h_state);
  ln_kernel<<<NB * SEQ / 4, 256, 0, stream>>>(hsb, gamma, beta, yb);
  // logits = y * head_w^T + head_b : M=4096, N=32000 (grid 32*250=8000, %8==0)
  gemm_bt_kernel<<<(NB * SEQ / BM) * (VOCAB / BN), 256, 0, stream>>>(
      yb, hwb, head_b, out, VOCAB, VOCAB / BN);
}

// Round 8
// 1956.790 us; speedup vs baseline: 1.0662x; 1.0662x over previous
//
#include <hip/hip_runtime.h>
#include <hip/hip_bf16.h>
#include <stdint.h>

#define VOCAB 32000
#define HID 512
#define NB 8
#define SEQ 512
#define NG 1536
#define LN_EPS 1e-5f
#define GRU_WGS 32
#define NWORK 224
#define TW 16
#define NTW (SEQ / TW)      // 32 t-windows
#define NBN (VOCAB / 128)   // 250 vocab tiles
#define GRU_SPIN_BUDGET (1 << 20)
#define WRK_SPIN_BUDGET (1 << 22)

typedef short bf16x8 __attribute__((ext_vector_type(8)));
typedef float f32x4 __attribute__((ext_vector_type(4)));

__device__ __forceinline__ unsigned short f2bf(float f) {
  union { float f; uint32_t u; } c; c.f = f;
  return (unsigned short)((c.u + 0x7fffu + ((c.u >> 16) & 1u)) >> 16);
}

// ---------------- init workspace (every launch: h_state=0, flags=0) ---------
__global__ void init_ws_kernel(unsigned short* h_state, int* flags) {
  int i = blockIdx.x * 256 + threadIdx.x;
  if (i < 2 * 16 * HID) h_state[i] = 0;
  if (i < GRU_WGS * 16) flags[i] = 0;
}

// ---------------- fp32 -> bf16 bulk convert ---------------------------------
__global__ void conv_bf16_kernel(const float* __restrict__ in,
                                 unsigned short* __restrict__ out, int n4) {
  int i = blockIdx.x * 256 + threadIdx.x;
  if (i >= n4) return;
  const float4 v = ((const float4*)in)[i];
  ushort4 o;
  o.x = f2bf(v.x); o.y = f2bf(v.y); o.z = f2bf(v.z); o.w = f2bf(v.w);
  ((ushort4*)out)[i] = o;
}

// ---------------- embedding gather -> bf16 A matrix [4096][512] -------------
__global__ void embed_kernel(const int* __restrict__ ids,
                             const float* __restrict__ emb,
                             unsigned short* __restrict__ out) {
  int row = blockIdx.x;
  int id = ids[row];
  int c = threadIdx.x * 2;
  const float2 v = *(const float2*)(emb + (size_t)id * HID + c);
  ushort2 o; o.x = f2bf(v.x); o.y = f2bf(v.y);
  *(ushort2*)(out + (size_t)row * HID + c) = o;
}

// ---------------- bf16 GEMM: C[M][N] = A[M][K] * B[N][K]^T + bias -----------
#define BM 128
#define BN 128
#define BK 32

__global__ __launch_bounds__(256, 2) void gemm_bt_kernel(
    const unsigned short* __restrict__ A, const unsigned short* __restrict__ B,
    const float* __restrict__ bias, float* __restrict__ C, int N, int nbn) {
  __shared__ unsigned short a_lds[BM * BK];
  __shared__ unsigned short b_lds[BN * BK];
  const int nwg = gridDim.x;
  const int chunk = nwg >> 3;
  const int bid = blockIdx.x;
  const int sw = (bid & 7) * chunk + (bid >> 3);
  const int bm = sw / nbn, bn = sw % nbn;
  const int tid = threadIdx.x;
  const int lane = tid & 63, wid = tid >> 6;
  const int wm = wid >> 1, wn = wid & 1;

  f32x4 acc[4][4] = {};

  for (int kt = 0; kt < HID / BK; ++kt) {
    __syncthreads();
#pragma unroll
    for (int p = 0; p < 2; ++p) {
      const int flat = (p * 256 + tid) * 16;  // byte offset in 8KB tile
      const int row = flat >> 6;              // 64B per row (32 bf16)
      const int kb = flat & 63;
      const char* ga =
          (const char*)(A + ((size_t)(bm * BM + row) * HID + kt * BK)) + kb;
      const char* gb =
          (const char*)(B + ((size_t)(bn * BN + row) * HID + kt * BK)) + kb;
      char* la = (char*)a_lds + (size_t)(p * 256 + wid * 64) * 16;
      char* lb = (char*)b_lds + (size_t)(p * 256 + wid * 64) * 16;
      __builtin_amdgcn_global_load_lds(
          (const __attribute__((address_space(1))) void*)ga,
          (__attribute__((address_space(3))) void*)la, 16, 0, 0);
      __builtin_amdgcn_global_load_lds(
          (const __attribute__((address_space(1))) void*)gb,
          (__attribute__((address_space(3))) void*)lb, 16, 0, 0);
    }
    __syncthreads();
    bf16x8 af[4], bfr[4];
#pragma unroll
    for (int i = 0; i < 4; ++i) {
      af[i] = *(const bf16x8*)(a_lds + (wm * 64 + i * 16 + (lane & 15)) * BK +
                               (lane >> 4) * 8);
      bfr[i] = *(const bf16x8*)(b_lds + (wn * 64 + i * 16 + (lane & 15)) * BK +
                                (lane >> 4) * 8);
    }
#pragma unroll
    for (int i = 0; i < 4; ++i)
#pragma unroll
      for (int j = 0; j < 4; ++j)
        acc[i][j] =
            __builtin_amdgcn_mfma_f32_16x16x32_bf16(af[i], bfr[j], acc[i][j], 0, 0, 0);
  }
#pragma unroll
  for (int i = 0; i < 4; ++i) {
    const int mrow = bm * BM + wm * 64 + i * 16 + (lane >> 4) * 4;
#pragma unroll
    for (int j = 0; j < 4; ++j) {
      const int col = bn * BN + wn * 64 + j * 16 + (lane & 15);
      const float bv = bias[col];
#pragma unroll
      for (int r = 0; r < 4; ++r)
        C[(size_t)(mrow + r) * N + col] = acc[i][j][r] + bv;
    }
  }
}

// ---------------- fused persistent mega-kernel -------------------------------
// Blocks 0..31: round-5 GRU (wave 0 only; 1 wave/WG, flag protocol, all
//   cross-WG traffic relaxed agent-scope = LLC). hs stores are agent-scope and
//   issued BEFORE the vmcnt(0) drain, so flags>=t+1 implies hs_t LLC-visible.
// Blocks 32..255: persistent LN+head-GEMM workers. Tile = 128 A-rows
//   {(b, t0+i) : b=0..7, i=0..15} x 128 vocab cols; unlocked when all 32 GRU
//   flags >= t0+16. LN is fused into A staging (stats pass + normalize).
//   Keeping 224 CUs busy with MFMA also holds DPM clocks up, which shortens
//   the GRU's serial LLC hops.
__global__ __launch_bounds__(256, 1) void mega_kernel(
    const float* __restrict__ xg, const float* __restrict__ w_hh,
    const float* __restrict__ b_hh, float* __restrict__ hs,
    unsigned short* __restrict__ h_state, int* __restrict__ flags,
    const unsigned short* __restrict__ hwb, const float* __restrict__ head_b,
    const float* __restrict__ gamma, const float* __restrict__ beta,
    float* __restrict__ out) {
  __shared__ float h_pub[8][16];
  __shared__ unsigned short a_lds[128 * 32];
  __shared__ unsigned short b_lds[128 * 32];
  __shared__ float mu_lds[128];
  __shared__ float is_lds[128];

  const int tid = threadIdx.x;

  if (blockIdx.x < GRU_WGS) {
    // =================== GRU path (wave 0 of blocks 0..31) ===================
    if (tid >= 64) return;
    const int wid = blockIdx.x;
    const int lane = tid;
    const int col16 = lane & 15;
    const int kq = lane >> 4;

    bf16x8 wf[3][16];
#pragma unroll
    for (int g = 0; g < 3; ++g) {
      const float* wr =
          w_hh + (size_t)(g * HID + wid * 16 + col16) * HID + kq * 8;
#pragma unroll
      for (int kk = 0; kk < 16; ++kk) {
        float4 f0 = *(const float4*)(wr + kk * 32);
        float4 f1 = *(const float4*)(wr + kk * 32 + 4);
        bf16x8 v;
        v[0] = (short)f2bf(f0.x); v[1] = (short)f2bf(f0.y);
        v[2] = (short)f2bf(f0.z); v[3] = (short)f2bf(f0.w);
        v[4] = (short)f2bf(f1.x); v[5] = (short)f2bf(f1.y);
        v[6] = (short)f2bf(f1.z); v[7] = (short)f2bf(f1.w);
        wf[g][kk] = v;
      }
    }
    const float bh_r = b_hh[0 * HID + wid * 16 + col16];
    const float bh_z = b_hh[1 * HID + wid * 16 + col16];
    const float bh_n = b_hh[2 * HID + wid * 16 + col16];

    const int abase = col16 * HID + kq * 8;
    const bool realrow = col16 < 8;
    const bool owner = lane < 32;
    const int bbase = kq * 4;

    float xr[4], xz[4], xn[4];
#pragma unroll
    for (int r = 0; r < 4; ++r) { xr[r] = 0.f; xz[r] = 0.f; xn[r] = 0.f; }
    if (owner) {
#pragma unroll
      for (int r = 0; r < 4; ++r) {
        const size_t xo = (size_t)(bbase + r) * SEQ * NG + wid * 16 + col16;
        xr[r] = xg[xo];
        xz[r] = xg[xo + HID];
        xn[r] = xg[xo + 2 * HID];
      }
    }
    float hprev[4] = {0.f, 0.f, 0.f, 0.f};
    int budget = GRU_SPIN_BUDGET;

    for (int t = 0; t < SEQ; ++t) {
      // ---- wait for h_t (flags >= t) ----
      while (budget > 0) {
        int v = t;
        if (lane < 32)
          v = __hip_atomic_load(flags + lane * 16, __ATOMIC_RELAXED,
                                __HIP_MEMORY_SCOPE_AGENT);
        if (__ballot(v >= t) == ~0ULL) break;
        --budget;
        __builtin_amdgcn_s_sleep(1);
      }

      const unsigned short* rd = h_state + (size_t)(t & 1) * (16 * HID);
      unsigned short* wpub = h_state + (size_t)((t + 1) & 1) * (16 * HID);

      // ---- bulk-load A fragments (one shot) ----
      uint64_t hb[32];
#pragma unroll
      for (int kk = 0; kk < 32; ++kk) hb[kk] = 0;
      if (realrow) {
#pragma unroll
        for (int kk = 0; kk < 16; ++kk) {
          const uint64_t* ap = (const uint64_t*)(rd + abase + kk * 32);
          hb[2 * kk] = __hip_atomic_load(ap, __ATOMIC_RELAXED,
                                         __HIP_MEMORY_SCOPE_AGENT);
          hb[2 * kk + 1] = __hip_atomic_load(ap + 1, __ATOMIC_RELAXED,
                                             __HIP_MEMORY_SCOPE_AGENT);
        }
      }

      // ---- three independent 16-deep MFMA chains (r, z, n) ----
      f32x4 ar = {0.f, 0.f, 0.f, 0.f};
      f32x4 az = {0.f, 0.f, 0.f, 0.f};
      f32x4 an = {0.f, 0.f, 0.f, 0.f};
#pragma unroll
      for (int kk = 0; kk < 16; ++kk) {
        union { uint64_t u[2]; bf16x8 v; } cv;
        cv.u[0] = hb[2 * kk]; cv.u[1] = hb[2 * kk + 1];
        ar = __builtin_amdgcn_mfma_f32_16x16x32_bf16(cv.v, wf[0][kk], ar, 0, 0, 0);
        az = __builtin_amdgcn_mfma_f32_16x16x32_bf16(cv.v, wf[1][kk], az, 0, 0, 0);
        an = __builtin_amdgcn_mfma_f32_16x16x32_bf16(cv.v, wf[2][kk], an, 0, 0, 0);
      }

      // ---- in-register gate math; hs agent-stores BEFORE the drain ----
      if (owner) {
#pragma unroll
        for (int r = 0; r < 4; ++r) {
          const float rg = 1.f / (1.f + __expf(-(xr[r] + ar[r] + bh_r)));
          const float zg = 1.f / (1.f + __expf(-(xz[r] + az[r] + bh_z)));
          const float a = xn[r] + rg * (an[r] + bh_n);
          const float e2 = __expf(-2.f * fabsf(a));
          const float nn = copysignf((1.f - e2) / (1.f + e2), a);
          const float hnew = (1.f - zg) * nn + zg * hprev[r];
          hprev[r] = hnew;
          h_pub[bbase + r][col16] = hnew;
          union { float f; uint32_t u; } cv; cv.f = hnew;
          uint32_t* hp = (uint32_t*)(hs + ((size_t)(bbase + r) * SEQ + t) * HID +
                                     wid * 16 + col16);
          __hip_atomic_store(hp, cv.u, __ATOMIC_RELAXED,
                             __HIP_MEMORY_SCOPE_AGENT);
        }
      }
      asm volatile("s_waitcnt lgkmcnt(0)" ::: "memory");
      __builtin_amdgcn_sched_barrier(0);
      // ---- within-wave transpose publish: 64 lanes x u32 (2 cols) ----
      {
        const int tb = lane >> 3;
        const int tc = (lane & 7) * 2;
        const float2 hp = *(const float2*)&h_pub[tb][tc];
        union { unsigned short s[2]; uint32_t u; } pk;
        pk.s[0] = f2bf(hp.x);
        pk.s[1] = f2bf(hp.y);
        uint32_t* dst = (uint32_t*)(wpub + tb * HID + wid * 16 + tc);
        __hip_atomic_store(dst, pk.u, __ATOMIC_RELAXED,
                           __HIP_MEMORY_SCOPE_AGENT);
      }
      asm volatile("s_waitcnt vmcnt(0)" ::: "memory");  // drain h + hs stores
      if (lane == 0)
        __hip_atomic_store(flags + wid * 16, t + 1, __ATOMIC_RELAXED,
                           __HIP_MEMORY_SCOPE_AGENT);
      // ---- prefetch next xg (hides under next poll) ----
      if (owner && t + 1 < SEQ) {
#pragma unroll
        for (int r = 0; r < 4; ++r) {
          const size_t xo = (size_t)(bbase + r) * SEQ * NG +
                            (size_t)(t + 1) * NG + wid * 16 + col16;
          xr[r] = xg[xo]; xz[r] = xg[xo + HID]; xn[r] = xg[xo + 2 * HID];
        }
      }
    }
    return;
  }

  // =================== worker path (blocks 32..255) ==========================
  const int w = blockIdx.x - GRU_WGS;
  const int lane = tid & 63, wv = tid >> 6;
  const int wm = wv >> 1, wn = wv & 1;

  for (int ti = w; ti < NTW * NBN; ti += NWORK) {
    const int twi = ti / NBN;
    const int bn = ti - twi * NBN;
    const int t0 = twi * TW;
    const int tneed = t0 + TW;

    // ---- wait until all 32 GRU WGs passed step t0+TW ----
    if (tid < 64) {
      int bud = WRK_SPIN_BUDGET;
      while (bud-- > 0) {
        int v = 0x7fffffff;
        if (lane < 32)
          v = __hip_atomic_load(flags + lane * 16, __ATOMIC_RELAXED,
                                __HIP_MEMORY_SCOPE_AGENT);
        if (__ballot(v >= tneed) == ~0ULL) break;
        __builtin_amdgcn_s_sleep(8);
      }
    }
    __syncthreads();

    // ---- LN stats for the 128 rows (agent loads; 1 wave per 32 rows) ----
    for (int rr = 0; rr < 32; ++rr) {
      const int i = wv * 32 + rr;
      const int grow = ((i >> 4) * SEQ) + t0 + (i & 15);
      const uint64_t* xp = (const uint64_t*)(hs + (size_t)grow * HID) + lane * 4;
      float s = 0.f, q = 0.f;
#pragma unroll
      for (int j = 0; j < 4; ++j) {
        union { uint64_t u; float f[2]; } cv;
        cv.u = __hip_atomic_load(xp + j, __ATOMIC_RELAXED,
                                 __HIP_MEMORY_SCOPE_AGENT);
        s += cv.f[0] + cv.f[1];
        q += cv.f[0] * cv.f[0] + cv.f[1] * cv.f[1];
      }
#pragma unroll
      for (int off = 32; off > 0; off >>= 1) {
        s += __shfl_xor(s, off);
        q += __shfl_xor(q, off);
      }
      if (lane == 0) {
        const float mu = s * (1.f / 512.f);
        mu_lds[i] = mu;
        is_lds[i] = rsqrtf(q * (1.f / 512.f) - mu * mu + LN_EPS);
      }
    }
    __syncthreads();

    f32x4 acc[4][4] = {};
    for (int kt = 0; kt < 16; ++kt) {
      __syncthreads();
      // B staging: hwb tile via global_load_lds (2 passes)
#pragma unroll
      for (int p = 0; p < 2; ++p) {
        const int flat = (p * 256 + tid) * 16;
        const int row = flat >> 6;
        const int kb = flat & 63;
        const char* gb =
            (const char*)(hwb + ((size_t)(bn * 128 + row) * HID + kt * 32)) + kb;
        char* lb = (char*)b_lds + (size_t)(p * 256 + wv * 64) * 16;
        __builtin_amdgcn_global_load_lds(
            (const __attribute__((address_space(1))) void*)gb,
            (__attribute__((address_space(3))) void*)lb, 16, 0, 0);
      }
      // A staging: hs fp32 (agent) -> LN normalize -> bf16 -> LDS
      {
        const int arow = tid >> 1, ah = (tid & 1) * 16;
        const int grow = ((arow >> 4) * SEQ) + t0 + (arow & 15);
        const uint64_t* ap =
            (const uint64_t*)(hs + (size_t)grow * HID + kt * 32 + ah);
        float av[16];
#pragma unroll
        for (int j = 0; j < 8; ++j) {
          union { uint64_t u; float f[2]; } cv;
          cv.u = __hip_atomic_load(ap + j, __ATOMIC_RELAXED,
                                   __HIP_MEMORY_SCOPE_AGENT);
          av[2 * j] = cv.f[0];
          av[2 * j + 1] = cv.f[1];
        }
        const float mu = mu_lds[arow], isv = is_lds[arow];
        const float* gp = gamma + kt * 32 + ah;
        const float* bp = beta + kt * 32 + ah;
        union { unsigned short s[16]; uint4 u[2]; } pk;
#pragma unroll
        for (int j = 0; j < 16; ++j)
          pk.s[j] = f2bf((av[j] - mu) * isv * gp[j] + bp[j]);
        uint4* ad = (uint4*)((char*)a_lds + arow * 64 + ah * 2);
        ad[0] = pk.u[0];
        ad[1] = pk.u[1];
      }
      __syncthreads();
      bf16x8 af[4], bfr[4];
#pragma unroll
      for (int i = 0; i < 4; ++i) {
        af[i] = *(const bf16x8*)(a_lds + (wm * 64 + i * 16 + (lane & 15)) * 32 +
                                 (lane >> 4) * 8);
        bfr[i] = *(const bf16x8*)(b_lds + (wn * 64 + i * 16 + (lane & 15)) * 32 +
                                  (lane >> 4) * 8);
      }
#pragma unroll
      for (int i = 0; i < 4; ++i)
#pragma unroll
        for (int j = 0; j < 4; ++j)
          acc[i][j] = __builtin_amdgcn_mfma_f32_16x16x32_bf16(af[i], bfr[j],
                                                              acc[i][j], 0, 0, 0);
    }
    // ---- epilogue: logits + head bias ----
#pragma unroll
    for (int i = 0; i < 4; ++i) {
#pragma unroll
      for (int j = 0; j < 4; ++j) {
        const int col = bn * 128 + wn * 64 + j * 16 + (lane & 15);
        const float bv = head_b[col];
#pragma unroll
        for (int r = 0; r < 4; ++r) {
          const int mrowl = wm * 64 + i * 16 + (lane >> 4) * 4 + r;
          const int grow = ((mrowl >> 4) * SEQ) + t0 + (mrowl & 15);
          out[(size_t)grow * VOCAB + col] = acc[i][j][r] + bv;
        }
      }
    }
  }
}

// ---------------- launch -----------------------------------------------------
extern "C" void kernel_launch(void* const* d_in, const int* in_sizes, int n_in,
                              void* d_out, int out_size, void* d_ws,
                              size_t ws_size, hipStream_t stream) {
  const int* ids = (const int*)d_in[0];
  const float* emb = (const float*)d_in[1];
  const float* w_ih = (const float*)d_in[2];
  const float* w_hh = (const float*)d_in[3];
  const float* b_ih = (const float*)d_in[4];
  const float* b_hh = (const float*)d_in[5];
  const float* gamma = (const float*)d_in[6];
  const float* beta = (const float*)d_in[7];
  const float* head_w = (const float*)d_in[8];
  const float* head_b = (const float*)d_in[9];
  float* out = (float*)d_out;

  char* ws = (char*)d_ws;
  size_t off = 0;
  auto alloc = [&](size_t bytes) -> void* {
    void* p = ws + off;
    off = (off + bytes + 255) & ~(size_t)255;
    return p;
  };
  int* flags = (int*)alloc(GRU_WGS * 16 * sizeof(int));
  unsigned short* h_state = (unsigned short*)alloc(2 * 16 * HID * 2);
  unsigned short* A1 = (unsigned short*)alloc((size_t)NB * SEQ * HID * 2);
  unsigned short* wihb = (unsigned short*)alloc((size_t)NG * HID * 2);
  unsigned short* hwb = (unsigned short*)alloc((size_t)VOCAB * HID * 2);
  float* xg = (float*)alloc((size_t)NB * SEQ * NG * 4);
  float* hsb = (float*)alloc((size_t)NB * SEQ * HID * 4);

  init_ws_kernel<<<64, 256, 0, stream>>>(h_state, flags);
  conv_bf16_kernel<<<(NG * HID / 4) / 256, 256, 0, stream>>>(w_ih, wihb,
                                                             NG * HID / 4);
  conv_bf16_kernel<<<(VOCAB * HID / 4) / 256, 256, 0, stream>>>(
      head_w, hwb, VOCAB * HID / 4);
  embed_kernel<<<NB * SEQ, 256, 0, stream>>>(ids, emb, A1);
  // xg = A1 * w_ih^T + b_ih : M=4096, N=1536  (grid 32*12=384, %8==0)
  gemm_bt_kernel<<<(NB * SEQ / BM) * (NG / BN), 256, 0, stream>>>(
      A1, wihb, b_ih, xg, NG, NG / BN);
  // fused GRU + LN + head GEMM
  mega_kernel<<<GRU_WGS + NWORK, 256, 0, stream>>>(
      xg, w_hh, b_hh, hsb, h_state, flags, hwb, head_b, gamma, beta, out);
}